// Round 5
// baseline (401.132 us; speedup 1.0000x reference)
//
#include <hip/hip_runtime.h>
#include <math.h>

#define N_NODES 50000
#define N_EDGES 800000
#define HDIM 128
#define NLAYERS 4
#define LN_EPS 1e-5f
#define EQUARTER (N_EDGES / 4)
#define SEG 64   // CSR slots per node (P(deg>64) ~ 1e-19 for Poisson(16))
#define FILLB ((EQUARTER + 255) / 256)   // 782 fill blocks
#define GEMMB ((N_NODES + 63) / 64)      // 782 gemm blocks

typedef __attribute__((ext_vector_type(8))) short short8;
typedef __attribute__((ext_vector_type(4))) float floatx4;

__device__ __forceinline__ ushort f2bf(float x) {
    unsigned b = __float_as_uint(x);
    unsigned r = b + 0x7fffu + ((b >> 16) & 1u);
    return (ushort)(r >> 16);
}
__device__ __forceinline__ float2 bf2f2(unsigned u) {
    return make_float2(__uint_as_float(u << 16), __uint_as_float(u & 0xffff0000u));
}

// ---------------- CSR build: padded segments, single scattered pass ----------------

__device__ __forceinline__ void fill_body(int bid, int tid, const int* __restrict__ src,
                                          const int* __restrict__ dst, int* __restrict__ cnt,
                                          ushort* __restrict__ csr16) {
    int t = bid * 256 + tid;
    if (t >= EQUARTER) return;
    int s0 = src[t],                d0 = dst[t];
    int s1 = src[t + EQUARTER],     d1 = dst[t + EQUARTER];
    int s2 = src[t + 2 * EQUARTER], d2 = dst[t + 2 * EQUARTER];
    int s3 = src[t + 3 * EQUARTER], d3 = dst[t + 3 * EQUARTER];
    int p0 = atomicAdd(&cnt[d0], 1);
    int p1 = atomicAdd(&cnt[d1], 1);
    int p2 = atomicAdd(&cnt[d2], 1);
    int p3 = atomicAdd(&cnt[d3], 1);
    if (p0 < SEG) csr16[d0 * SEG + p0] = (ushort)s0;
    if (p1 < SEG) csr16[d1 * SEG + p1] = (ushort)s1;
    if (p2 < SEG) csr16[d2 * SEG + p2] = (ushort)s2;
    if (p3 < SEG) csr16[d3 * SEG + p3] = (ushort)s3;
}

__global__ __launch_bounds__(256) void isd_kernel(const int* __restrict__ cnt,
                                                  float* __restrict__ isd,
                                                  float* __restrict__ ind) {
    int i = blockIdx.x * 256 + threadIdx.x;
    if (i < N_NODES) {
        float d = (float)cnt[i] + 1.0f;  // self-loop
        isd[i] = rsqrtf(d);
        ind[i] = 1.0f / d;
    }
}

// ---------------- W -> MFMA B-fragment layout (bf16), once per launch ----------------
__global__ __launch_bounds__(256) void bprep_kernel(const float* __restrict__ W,
                                                    ushort* __restrict__ bfrag) {
    int idx = blockIdx.x * 256 + threadIdx.x;
    if (idx >= NLAYERS * 4 * 8 * 64) return;
    int lane = idx & 63;
    int t = (idx >> 6) & 7;
    int s = (idx >> 9) & 3;
    int l = idx >> 11;
    int n = t * 16 + (lane & 15);
    int kb = s * 32 + (lane >> 4) * 8;
    const float* Wl = W + (size_t)l * HDIM * HDIM;
    union { uint4 q; ushort u[8]; } o;
#pragma unroll
    for (int j = 0; j < 8; ++j) o.u[j] = f2bf(Wl[(size_t)(kb + j) * HDIM + n]);
    *(uint4*)&bfrag[(size_t)idx * 8] = o.q;
}

// ---------------- GEMM body: hw_bf16 = A @ W  via MFMA 16x16x32 bf16 ----------------
template <bool A_FP32>
__device__ __forceinline__ void gemm_body(int bid, int tid, const void* __restrict__ Av,
                                          const ushort* __restrict__ bfrag,
                                          ushort* __restrict__ out) {
    int wave = tid >> 6, lane = tid & 63;
    int quad = lane >> 4, mrow = lane & 15;
    int rowBase = bid * 64 + wave * 16;
    int arow = rowBase + mrow;
    bool aok = arow < N_NODES;

    floatx4 acc[8];
#pragma unroll
    for (int t = 0; t < 8; ++t) acc[t] = (floatx4)0.f;

#pragma unroll
    for (int s = 0; s < 4; ++s) {
        union { short8 v; ushort u[8]; } af;
        if (A_FP32) {
            const float* A = (const float*)Av;
            if (aok) {
                const float* p = &A[(size_t)arow * HDIM + s * 32 + quad * 8];
#pragma unroll
                for (int j = 0; j < 8; ++j) af.u[j] = f2bf(p[j]);
            } else {
#pragma unroll
                for (int j = 0; j < 8; ++j) af.u[j] = 0;
            }
        } else {
            const ushort* A = (const ushort*)Av;
            if (aok) {
                af.v = *(const short8*)&A[(size_t)arow * HDIM + s * 32 + quad * 8];
            } else {
#pragma unroll
                for (int j = 0; j < 8; ++j) af.u[j] = 0;
            }
        }
#pragma unroll
        for (int t = 0; t < 8; ++t) {
            short8 bf = *(const short8*)&bfrag[(size_t)(((s * 8 + t) * 64) + lane) * 8];
            acc[t] = __builtin_amdgcn_mfma_f32_16x16x32_bf16(af.v, bf, acc[t], 0, 0, 0);
        }
    }
#pragma unroll
    for (int t = 0; t < 8; ++t) {
#pragma unroll
        for (int r = 0; r < 4; ++r) {
            int row = rowBase + quad * 4 + r;
            if (row < N_NODES) out[(size_t)row * HDIM + t * 16 + mrow] = f2bf(acc[t][r]);
        }
    }
}

// Fused: fill (independent) overlapped with layer-0 GEMM (independent).
__global__ __launch_bounds__(256) void fused0_kernel(
    const int* __restrict__ src, const int* __restrict__ dst, int* __restrict__ cnt,
    ushort* __restrict__ csr16, const float* __restrict__ x,
    const ushort* __restrict__ bfrag0, ushort* __restrict__ hw) {
    if (blockIdx.x < FILLB)
        fill_body(blockIdx.x, threadIdx.x, src, dst, cnt, csr16);
    else
        gemm_body<true>(blockIdx.x - FILLB, threadIdx.x, x, bfrag0, hw);
}

// ---------------- Fused aggregate + self-loop + bias + LN (+GELU / +head) ----------------
// Layer 0 only (operates on hw0 = x @ W0 which was overlapped with the CSR fill).
__global__ __launch_bounds__(256) void agg_ln_kernel(
    const uint2* __restrict__ hw2, const int* __restrict__ degcnt,
    const ushort* __restrict__ csr16, const float* __restrict__ isd,
    const float* __restrict__ ind, const float* __restrict__ conv_b,
    const float* __restrict__ ln_g, const float* __restrict__ ln_b,
    uint2* __restrict__ hout_bf, float* __restrict__ hout_f32,
    const float* __restrict__ head_w, const float* __restrict__ head_b,
    float* __restrict__ scores, int final_layer) {
    int wave = threadIdx.x >> 6;
    int lane = threadIdx.x & 63;
    int g = lane >> 5;   // edge-parity group
    int li = lane & 31;  // lane in group; owns cols li*4 .. li*4+3
    int n = blockIdx.x * 4 + wave;
    if (n >= N_NODES) return;
    int c = li * 4;

    float isd_n = isd[n], ind_n = ind[n];
    int rs = n * SEG;
    int deg = min(degcnt[n], SEG);

    float e0 = 0.f, e1 = 0.f, e2 = 0.f, e3 = 0.f;
    int sj = 0;
    float wj = 0.f;
    if (lane < deg) {
        sj = (int)csr16[rs + lane];
        wj = isd[sj];
    }
    for (int j = 0; j < deg; j += 8) {
#pragma unroll
        for (int t = 0; t < 4; ++t) {
            int idx = j + 2 * t + g;
            int s = __shfl(sj, idx);
            float w = __shfl(wj, idx);
            uint2 u = hw2[(size_t)s * 32 + li];
            float2 q0 = bf2f2(u.x), q1 = bf2f2(u.y);
            e0 = fmaf(q0.x, w, e0); e1 = fmaf(q0.y, w, e1);
            e2 = fmaf(q1.x, w, e2); e3 = fmaf(q1.y, w, e3);
        }
    }
    e0 += __shfl_xor(e0, 32); e1 += __shfl_xor(e1, 32);
    e2 += __shfl_xor(e2, 32); e3 += __shfl_xor(e3, 32);

    uint2 hv = hw2[(size_t)n * 32 + li];
    float2 h0 = bf2f2(hv.x), h1 = bf2f2(hv.y);
    float4 cb = *(const float4*)&conv_b[c];
    float a0 = fmaf(e0, isd_n, fmaf(h0.x, ind_n, cb.x));
    float a1 = fmaf(e1, isd_n, fmaf(h0.y, ind_n, cb.y));
    float a2 = fmaf(e2, isd_n, fmaf(h1.x, ind_n, cb.z));
    float a3 = fmaf(e3, isd_n, fmaf(h1.y, ind_n, cb.w));

    float sum = a0 + a1 + a2 + a3;
#pragma unroll
    for (int o = 1; o < 32; o <<= 1) sum += __shfl_xor(sum, o);
    float mu = sum * (1.0f / HDIM);
    float d0 = a0 - mu, d1 = a1 - mu, d2 = a2 - mu, d3 = a3 - mu;
    float vs = d0 * d0 + d1 * d1 + d2 * d2 + d3 * d3;
#pragma unroll
    for (int o = 1; o < 32; o <<= 1) vs += __shfl_xor(vs, o);
    float rstd = rsqrtf(vs * (1.0f / HDIM) + LN_EPS);
    float4 gv = *(const float4*)&ln_g[c];
    float4 bv = *(const float4*)&ln_b[c];
    float y0 = fmaf(d0 * rstd, gv.x, bv.x);
    float y1 = fmaf(d1 * rstd, gv.y, bv.y);
    float y2 = fmaf(d2 * rstd, gv.z, bv.z);
    float y3 = fmaf(d3 * rstd, gv.w, bv.w);

    if (!final_layer) {
#define GELU(v) ((v) = 0.5f * (v) * (1.0f + erff((v) * 0.70710678118654752f)))
        GELU(y0); GELU(y1); GELU(y2); GELU(y3);
#undef GELU
        if (g == 0) {
            uint2 ov;
            ov.x = (unsigned)f2bf(y0) | ((unsigned)f2bf(y1) << 16);
            ov.y = (unsigned)f2bf(y2) | ((unsigned)f2bf(y3) << 16);
            hout_bf[(size_t)n * 32 + li] = ov;
        }
    } else {
        if (g == 0)
            *(float4*)&hout_f32[(size_t)n * HDIM + c] = make_float4(y0, y1, y2, y3);
        float4 hwv = *(const float4*)&head_w[c];
        float p = y0 * hwv.x + y1 * hwv.y + y2 * hwv.z + y3 * hwv.w;
#pragma unroll
        for (int o = 1; o < 32; o <<= 1) p += __shfl_xor(p, o);
        if (lane == 0) scores[n] = p + head_b[0];
    }
}

// ---------------- Fully fused layer: agg(H) -> @W -> +b -> LN -> (GELU | head) ------
// 8 waves / 512 threads, 64 nodes per block. Phase 1: wave w aggregates nodes
// w*8..w*8+7 into f32 LDS rows, with next-node csr/isd prefetch and next-iteration
// row-load double-buffering (memory-level parallelism). Phase 2: wave PAIRS split
// the GEMM (rows (w>>1)*16..+15, column half (w&1)). Phase 3: +bias, store back via
// the verified gemm_body mapping. Phase 4: verbatim agg_ln LayerNorm per node.
// Cross-wave LDS sharing => __syncthreads() between phases.
__global__ __launch_bounds__(512) void layer_fused_kernel(
    const uint2* __restrict__ h2, const int* __restrict__ degcnt,
    const ushort* __restrict__ csr16, const float* __restrict__ isd,
    const float* __restrict__ ind, const ushort* __restrict__ bfrag,
    const float* __restrict__ conv_b, const float* __restrict__ ln_g,
    const float* __restrict__ ln_b, uint2* __restrict__ hout_bf,
    float* __restrict__ hout_f32, const float* __restrict__ head_w,
    const float* __restrict__ head_b, float* __restrict__ scores,
    int final_layer) {
    __shared__ float aggsf[64][132];  // f32 rows; +4 pad floats per row (528 B rows)
    int wave = threadIdx.x >> 6, lane = threadIdx.x & 63;
    int g = lane >> 5, li = lane & 31;

    // ---- phase 1: aggregate 8 nodes per wave, pipelined ----
    int nodeBase = blockIdx.x * 64 + wave * 8;
    // prologue: prefetch node 0's deg/csr/isd (tail lanes masked to sj=0,wj=0,
    // exactly the verified agg_ln staging semantics)
    int deg_c = 0, sj_c = 0;
    float wj_c = 0.f;
    if (nodeBase < N_NODES) {
        deg_c = min(degcnt[nodeBase], SEG);
        int sraw = (int)csr16[nodeBase * SEG + lane];
        sj_c = (lane < deg_c) ? sraw : 0;
        float w = isd[sj_c];
        wj_c = (lane < deg_c) ? w : 0.f;
    }
    for (int it = 0; it < 8; ++it) {
        int n = nodeBase + it;
        int deg = deg_c, sj = sj_c;
        float wj = wj_c;
        // issue next node's deg+csr loads now; finish (isd) after the gather
        int deg_nx = 0, sraw_nx = 0;
        if (it < 7 && (n + 1) < N_NODES) {
            deg_nx = min(degcnt[n + 1], SEG);
            sraw_nx = (int)csr16[(n + 1) * SEG + lane];
        }
        float a0 = 0.f, a1 = 0.f, a2 = 0.f, a3 = 0.f;
        if (n < N_NODES) {
            float isd_n = isd[n], ind_n = ind[n];
            uint2 hv = h2[(size_t)n * 32 + li];
            float e0 = 0.f, e1 = 0.f, e2 = 0.f, e3 = 0.f;
            // preload iteration j=0's rows (tail idx -> row 0, weight 0)
            uint2 u[4];
#pragma unroll
            for (int t = 0; t < 4; ++t) {
                int s = __shfl(sj, 2 * t + g);
                u[t] = h2[(size_t)s * 32 + li];
            }
            for (int j = 0; j < deg; j += 8) {
                uint2 un[4];
                int jn = j + 8;
                bool more = jn < deg;  // wave-uniform
                if (more) {
#pragma unroll
                    for (int t = 0; t < 4; ++t) {
                        int s = __shfl(sj, jn + 2 * t + g);  // jn<=56 -> idx<=63
                        un[t] = h2[(size_t)s * 32 + li];
                    }
                }
#pragma unroll
                for (int t = 0; t < 4; ++t) {
                    float w = __shfl(wj, j + 2 * t + g);
                    float2 q0 = bf2f2(u[t].x), q1 = bf2f2(u[t].y);
                    e0 = fmaf(q0.x, w, e0); e1 = fmaf(q0.y, w, e1);
                    e2 = fmaf(q1.x, w, e2); e3 = fmaf(q1.y, w, e3);
                }
                if (more) { u[0] = un[0]; u[1] = un[1]; u[2] = un[2]; u[3] = un[3]; }
            }
            e0 += __shfl_xor(e0, 32); e1 += __shfl_xor(e1, 32);
            e2 += __shfl_xor(e2, 32); e3 += __shfl_xor(e3, 32);
            float2 h0 = bf2f2(hv.x), h1v = bf2f2(hv.y);
            a0 = fmaf(e0, isd_n, h0.x * ind_n);
            a1 = fmaf(e1, isd_n, h0.y * ind_n);
            a2 = fmaf(e2, isd_n, h1v.x * ind_n);
            a3 = fmaf(e3, isd_n, h1v.y * ind_n);
        }
        if (g == 0)
            *(float4*)&aggsf[wave * 8 + it][li * 4] = make_float4(a0, a1, a2, a3);
        // finish next-node prefetch: mask stale lanes, gather isd
        deg_c = deg_nx;
        sj_c = (lane < deg_nx) ? sraw_nx : 0;
        float w = isd[sj_c];
        wj_c = (lane < deg_nx) ? w : 0.f;
    }
    __syncthreads();  // pair waves read each other's agg rows

    // ---- phase 2: GEMM (split hi/lo bf16 A from f32 LDS) @ (bfrag B) ----
    // wave pair (2k,2k+1): rows 16k..16k+15; column half = wave&1 (t = chalf..chalf+3)
    int quad = lane >> 4, mrow = lane & 15;
    int rtile = (wave >> 1) * 16;
    int chalf = (wave & 1) * 4;
    floatx4 acc[4];
#pragma unroll
    for (int t = 0; t < 4; ++t) acc[t] = (floatx4)0.f;
#pragma unroll
    for (int s = 0; s < 4; ++s) {
        const float* rowp = &aggsf[rtile + mrow][s * 32 + quad * 8];
        float4 pa = *(const float4*)rowp;
        float4 pb = *(const float4*)(rowp + 4);
        float p[8] = {pa.x, pa.y, pa.z, pa.w, pb.x, pb.y, pb.z, pb.w};
        union { short8 v; ushort u[8]; } hi, lo;
#pragma unroll
        for (int j = 0; j < 8; ++j) {
            ushort h = f2bf(p[j]);
            hi.u[j] = h;
            float hf = __uint_as_float((unsigned)h << 16);
            lo.u[j] = f2bf(p[j] - hf);  // exact residual (Sterbenz), then 1 round
        }
#pragma unroll
        for (int t4 = 0; t4 < 4; ++t4) {
            int t = chalf + t4;
            short8 bf = *(const short8*)&bfrag[(size_t)(((s * 8 + t) * 64) + lane) * 8];
            acc[t4] = __builtin_amdgcn_mfma_f32_16x16x32_bf16(lo.v, bf, acc[t4], 0, 0, 0);
            acc[t4] = __builtin_amdgcn_mfma_f32_16x16x32_bf16(hi.v, bf, acc[t4], 0, 0, 0);
        }
    }
    __syncthreads();  // all reads of agg rows done before overwrite

    // ---- phase 3: +bias, store acc back to LDS rows (verified gemm_body mapping) ----
    {
        float cb[4];
#pragma unroll
        for (int t4 = 0; t4 < 4; ++t4) cb[t4] = conv_b[(chalf + t4) * 16 + mrow];
#pragma unroll
        for (int t4 = 0; t4 < 4; ++t4)
#pragma unroll
            for (int r = 0; r < 4; ++r)
                aggsf[rtile + quad * 4 + r][(chalf + t4) * 16 + mrow] = acc[t4][r] + cb[t4];
    }
    __syncthreads();  // LN reads full rows written by the wave pair

    // ---- phase 4: per-node LN from LDS — verbatim agg_ln pattern, 8 nodes/wave ----
    int c = li * 4;
    float4 gv = *(const float4*)&ln_g[c];
    float4 bv = *(const float4*)&ln_b[c];
    float4 hwv = *(const float4*)&head_w[c];
    for (int it = 0; it < 8; ++it) {
        int row = wave * 8 + it;
        int n = blockIdx.x * 64 + row;
        if (n >= N_NODES) continue;  // wave-uniform
        float4 v = *(const float4*)&aggsf[row][c];
        float a0 = v.x, a1 = v.y, a2 = v.z, a3 = v.w;

        float sum = a0 + a1 + a2 + a3;
#pragma unroll
        for (int o = 1; o < 32; o <<= 1) sum += __shfl_xor(sum, o);
        float mu = sum * (1.0f / HDIM);
        float d0 = a0 - mu, d1 = a1 - mu, d2 = a2 - mu, d3 = a3 - mu;
        float vs = d0 * d0 + d1 * d1 + d2 * d2 + d3 * d3;
#pragma unroll
        for (int o = 1; o < 32; o <<= 1) vs += __shfl_xor(vs, o);
        float rstd = rsqrtf(vs * (1.0f / HDIM) + LN_EPS);
        float y0 = fmaf(d0 * rstd, gv.x, bv.x);
        float y1 = fmaf(d1 * rstd, gv.y, bv.y);
        float y2 = fmaf(d2 * rstd, gv.z, bv.z);
        float y3 = fmaf(d3 * rstd, gv.w, bv.w);

        if (!final_layer) {
#define GELU(v) ((v) = 0.5f * (v) * (1.0f + erff((v) * 0.70710678118654752f)))
            GELU(y0); GELU(y1); GELU(y2); GELU(y3);
#undef GELU
            if (g == 0) {
                uint2 ov;
                ov.x = (unsigned)f2bf(y0) | ((unsigned)f2bf(y1) << 16);
                ov.y = (unsigned)f2bf(y2) | ((unsigned)f2bf(y3) << 16);
                hout_bf[(size_t)n * 32 + li] = ov;
            }
        } else {
            if (g == 0)
                *(float4*)&hout_f32[(size_t)n * HDIM + c] = make_float4(y0, y1, y2, y3);
            float p = y0 * hwv.x + y1 * hwv.y + y2 * hwv.z + y3 * hwv.w;
#pragma unroll
            for (int o = 1; o < 32; o <<= 1) p += __shfl_xor(p, o);
            if (lane == 0) scores[n] = p + head_b[0];
        }
    }
}

// ---------------- host ----------------

extern "C" void kernel_launch(void* const* d_in, const int* in_sizes, int n_in,
                              void* d_out, int out_size, void* d_ws, size_t ws_size,
                              hipStream_t stream) {
    const float* x      = (const float*)d_in[0];
    const int*   eidx   = (const int*)d_in[1];
    const float* conv_w = (const float*)d_in[2];
    const float* conv_b = (const float*)d_in[3];
    const float* ln_g   = (const float*)d_in[4];
    const float* ln_b   = (const float*)d_in[5];
    const float* head_w = (const float*)d_in[6];
    const float* head_b = (const float*)d_in[7];
    float* out = (float*)d_out;  // [N scores][N*H h]

    const int* src = eidx;
    const int* dst = eidx + N_EDGES;

    char* ws = (char*)d_ws;
    size_t o = 0;
    auto alloc = [&](size_t elems) {  // elems of 4 bytes
        void* p = ws + o * 4;
        o += (elems + 15) & ~(size_t)15;
        return p;
    };
    int*      cnt      = (int*)alloc(N_NODES);
    float*    isd      = (float*)alloc(N_NODES);
    float*    ind      = (float*)alloc(N_NODES);
    ushort*   csr16    = (ushort*)alloc((size_t)N_NODES * SEG / 2);
    ushort*   bfrag    = (ushort*)alloc(NLAYERS * 4 * 8 * 64 * 8 / 2);
    unsigned* hw       = (unsigned*)alloc((size_t)N_NODES * 64);   // bf16 N x 128
    unsigned* hbuf     = (unsigned*)alloc((size_t)N_NODES * 64);   // bf16 N x 128

    hipMemsetAsync(cnt, 0, N_NODES * sizeof(int), stream);
    bprep_kernel<<<(NLAYERS * 4 * 8 * 64 + 255) / 256, 256, 0, stream>>>(conv_w, bfrag);
    fused0_kernel<<<FILLB + GEMMB, 256, 0, stream>>>(src, dst, cnt, csr16, x, bfrag,
                                                     (ushort*)hw);
    isd_kernel<<<(N_NODES + 255) / 256, 256, 0, stream>>>(cnt, isd, ind);

    // layer 0: aggregate hw0 (= x @ W0, computed under the fill) + LN + GELU -> hbuf
    agg_ln_kernel<<<(N_NODES + 3) / 4, 256, 0, stream>>>(
        (const uint2*)hw, cnt, csr16, isd, ind,
        conv_b, ln_g, ln_b,
        (uint2*)hbuf, out + N_NODES, head_w, head_b, out, 0);

    // layers 1..3: fused agg -> GEMM -> LN (+GELU | +head), ping-pong hbuf/hw
    const unsigned* hin = hbuf;
    unsigned* hnext = hw;
    for (int l = 1; l < NLAYERS; ++l) {
        const ushort* bl = bfrag + (size_t)l * 4 * 8 * 64 * 8;
        int fin = (l == NLAYERS - 1) ? 1 : 0;
        layer_fused_kernel<<<GEMMB, 512, 0, stream>>>(
            (const uint2*)hin, cnt, csr16, isd, ind, bl,
            conv_b + (size_t)l * HDIM, ln_g + (size_t)l * HDIM, ln_b + (size_t)l * HDIM,
            (uint2*)hnext, out + N_NODES, head_w, head_b, out, fin);
        const unsigned* tmp = hin;
        hin = hnext;
        hnext = (unsigned*)tmp;
    }
}

// Round 6
// 361.877 us; speedup vs baseline: 1.1085x; 1.1085x over previous
//
#include <hip/hip_runtime.h>
#include <math.h>

#define N_NODES 50000
#define N_EDGES 800000
#define HDIM 128
#define NLAYERS 4
#define LN_EPS 1e-5f
#define EQUARTER (N_EDGES / 4)
#define SEG 64   // CSR slots per node (P(deg>64) ~ 1e-19 for Poisson(16))
#define FILLB ((EQUARTER + 255) / 256)   // 782 fill blocks
#define GEMMB ((N_NODES + 63) / 64)      // 782 gemm blocks
#define LFB ((N_NODES + 31) / 32)        // 1563 fused-layer blocks (32-node tiles)

typedef __attribute__((ext_vector_type(8))) short short8;
typedef __attribute__((ext_vector_type(4))) float floatx4;

__device__ __forceinline__ ushort f2bf(float x) {
    unsigned b = __float_as_uint(x);
    unsigned r = b + 0x7fffu + ((b >> 16) & 1u);
    return (ushort)(r >> 16);
}
__device__ __forceinline__ float2 bf2f2(unsigned u) {
    return make_float2(__uint_as_float(u << 16), __uint_as_float(u & 0xffff0000u));
}

// ---------------- CSR build: padded segments, single scattered pass ----------------

__device__ __forceinline__ void fill_body(int bid, int tid, const int* __restrict__ src,
                                          const int* __restrict__ dst, int* __restrict__ cnt,
                                          ushort* __restrict__ csr16) {
    int t = bid * 256 + tid;
    if (t >= EQUARTER) return;
    int s0 = src[t],                d0 = dst[t];
    int s1 = src[t + EQUARTER],     d1 = dst[t + EQUARTER];
    int s2 = src[t + 2 * EQUARTER], d2 = dst[t + 2 * EQUARTER];
    int s3 = src[t + 3 * EQUARTER], d3 = dst[t + 3 * EQUARTER];
    int p0 = atomicAdd(&cnt[d0], 1);
    int p1 = atomicAdd(&cnt[d1], 1);
    int p2 = atomicAdd(&cnt[d2], 1);
    int p3 = atomicAdd(&cnt[d3], 1);
    if (p0 < SEG) csr16[d0 * SEG + p0] = (ushort)s0;
    if (p1 < SEG) csr16[d1 * SEG + p1] = (ushort)s1;
    if (p2 < SEG) csr16[d2 * SEG + p2] = (ushort)s2;
    if (p3 < SEG) csr16[d3 * SEG + p3] = (ushort)s3;
}

__global__ __launch_bounds__(256) void isd_kernel(const int* __restrict__ cnt,
                                                  float* __restrict__ isd,
                                                  float* __restrict__ ind) {
    int i = blockIdx.x * 256 + threadIdx.x;
    if (i < N_NODES) {
        float d = (float)cnt[i] + 1.0f;  // self-loop
        isd[i] = rsqrtf(d);
        ind[i] = 1.0f / d;
    }
}

// ---------------- W -> MFMA B-fragment layout (bf16), once per launch ----------------
__global__ __launch_bounds__(256) void bprep_kernel(const float* __restrict__ W,
                                                    ushort* __restrict__ bfrag) {
    int idx = blockIdx.x * 256 + threadIdx.x;
    if (idx >= NLAYERS * 4 * 8 * 64) return;
    int lane = idx & 63;
    int t = (idx >> 6) & 7;
    int s = (idx >> 9) & 3;
    int l = idx >> 11;
    int n = t * 16 + (lane & 15);
    int kb = s * 32 + (lane >> 4) * 8;
    const float* Wl = W + (size_t)l * HDIM * HDIM;
    union { uint4 q; ushort u[8]; } o;
#pragma unroll
    for (int j = 0; j < 8; ++j) o.u[j] = f2bf(Wl[(size_t)(kb + j) * HDIM + n]);
    *(uint4*)&bfrag[(size_t)idx * 8] = o.q;
}

// ---------------- GEMM body: hw_bf16 = A @ W  via MFMA 16x16x32 bf16 ----------------
template <bool A_FP32>
__device__ __forceinline__ void gemm_body(int bid, int tid, const void* __restrict__ Av,
                                          const ushort* __restrict__ bfrag,
                                          ushort* __restrict__ out) {
    int wave = tid >> 6, lane = tid & 63;
    int quad = lane >> 4, mrow = lane & 15;
    int rowBase = bid * 64 + wave * 16;
    int arow = rowBase + mrow;
    bool aok = arow < N_NODES;

    floatx4 acc[8];
#pragma unroll
    for (int t = 0; t < 8; ++t) acc[t] = (floatx4)0.f;

#pragma unroll
    for (int s = 0; s < 4; ++s) {
        union { short8 v; ushort u[8]; } af;
        if (A_FP32) {
            const float* A = (const float*)Av;
            if (aok) {
                const float* p = &A[(size_t)arow * HDIM + s * 32 + quad * 8];
#pragma unroll
                for (int j = 0; j < 8; ++j) af.u[j] = f2bf(p[j]);
            } else {
#pragma unroll
                for (int j = 0; j < 8; ++j) af.u[j] = 0;
            }
        } else {
            const ushort* A = (const ushort*)Av;
            if (aok) {
                af.v = *(const short8*)&A[(size_t)arow * HDIM + s * 32 + quad * 8];
            } else {
#pragma unroll
                for (int j = 0; j < 8; ++j) af.u[j] = 0;
            }
        }
#pragma unroll
        for (int t = 0; t < 8; ++t) {
            short8 bf = *(const short8*)&bfrag[(size_t)(((s * 8 + t) * 64) + lane) * 8];
            acc[t] = __builtin_amdgcn_mfma_f32_16x16x32_bf16(af.v, bf, acc[t], 0, 0, 0);
        }
    }
#pragma unroll
    for (int t = 0; t < 8; ++t) {
#pragma unroll
        for (int r = 0; r < 4; ++r) {
            int row = rowBase + quad * 4 + r;
            if (row < N_NODES) out[(size_t)row * HDIM + t * 16 + mrow] = f2bf(acc[t][r]);
        }
    }
}

// Fused: fill (independent) overlapped with layer-0 GEMM (independent).
__global__ __launch_bounds__(256) void fused0_kernel(
    const int* __restrict__ src, const int* __restrict__ dst, int* __restrict__ cnt,
    ushort* __restrict__ csr16, const float* __restrict__ x,
    const ushort* __restrict__ bfrag0, ushort* __restrict__ hw) {
    if (blockIdx.x < FILLB)
        fill_body(blockIdx.x, threadIdx.x, src, dst, cnt, csr16);
    else
        gemm_body<true>(blockIdx.x - FILLB, threadIdx.x, x, bfrag0, hw);
}

// ---------------- Fused aggregate + self-loop + bias + LN (+GELU / +head) ----------------
// Layer 0 only (operates on hw0 = x @ W0 which was overlapped with the CSR fill).
__global__ __launch_bounds__(256) void agg_ln_kernel(
    const uint2* __restrict__ hw2, const int* __restrict__ degcnt,
    const ushort* __restrict__ csr16, const float* __restrict__ isd,
    const float* __restrict__ ind, const float* __restrict__ conv_b,
    const float* __restrict__ ln_g, const float* __restrict__ ln_b,
    uint2* __restrict__ hout_bf, float* __restrict__ hout_f32,
    const float* __restrict__ head_w, const float* __restrict__ head_b,
    float* __restrict__ scores, int final_layer) {
    int wave = threadIdx.x >> 6;
    int lane = threadIdx.x & 63;
    int g = lane >> 5;   // edge-parity group
    int li = lane & 31;  // lane in group; owns cols li*4 .. li*4+3
    int n = blockIdx.x * 4 + wave;
    if (n >= N_NODES) return;
    int c = li * 4;

    float isd_n = isd[n], ind_n = ind[n];
    int rs = n * SEG;
    int deg = min(degcnt[n], SEG);

    float e0 = 0.f, e1 = 0.f, e2 = 0.f, e3 = 0.f;
    int sj = 0;
    float wj = 0.f;
    if (lane < deg) {
        sj = (int)csr16[rs + lane];
        wj = isd[sj];
    }
    for (int j = 0; j < deg; j += 8) {
#pragma unroll
        for (int t = 0; t < 4; ++t) {
            int idx = j + 2 * t + g;
            int s = __shfl(sj, idx);
            float w = __shfl(wj, idx);
            uint2 u = hw2[(size_t)s * 32 + li];
            float2 q0 = bf2f2(u.x), q1 = bf2f2(u.y);
            e0 = fmaf(q0.x, w, e0); e1 = fmaf(q0.y, w, e1);
            e2 = fmaf(q1.x, w, e2); e3 = fmaf(q1.y, w, e3);
        }
    }
    e0 += __shfl_xor(e0, 32); e1 += __shfl_xor(e1, 32);
    e2 += __shfl_xor(e2, 32); e3 += __shfl_xor(e3, 32);

    uint2 hv = hw2[(size_t)n * 32 + li];
    float2 h0 = bf2f2(hv.x), h1 = bf2f2(hv.y);
    float4 cb = *(const float4*)&conv_b[c];
    float a0 = fmaf(e0, isd_n, fmaf(h0.x, ind_n, cb.x));
    float a1 = fmaf(e1, isd_n, fmaf(h0.y, ind_n, cb.y));
    float a2 = fmaf(e2, isd_n, fmaf(h1.x, ind_n, cb.z));
    float a3 = fmaf(e3, isd_n, fmaf(h1.y, ind_n, cb.w));

    float sum = a0 + a1 + a2 + a3;
#pragma unroll
    for (int o = 1; o < 32; o <<= 1) sum += __shfl_xor(sum, o);
    float mu = sum * (1.0f / HDIM);
    float d0 = a0 - mu, d1 = a1 - mu, d2 = a2 - mu, d3 = a3 - mu;
    float vs = d0 * d0 + d1 * d1 + d2 * d2 + d3 * d3;
#pragma unroll
    for (int o = 1; o < 32; o <<= 1) vs += __shfl_xor(vs, o);
    float rstd = rsqrtf(vs * (1.0f / HDIM) + LN_EPS);
    float4 gv = *(const float4*)&ln_g[c];
    float4 bv = *(const float4*)&ln_b[c];
    float y0 = fmaf(d0 * rstd, gv.x, bv.x);
    float y1 = fmaf(d1 * rstd, gv.y, bv.y);
    float y2 = fmaf(d2 * rstd, gv.z, bv.z);
    float y3 = fmaf(d3 * rstd, gv.w, bv.w);

    if (!final_layer) {
#define GELU(v) ((v) = 0.5f * (v) * (1.0f + erff((v) * 0.70710678118654752f)))
        GELU(y0); GELU(y1); GELU(y2); GELU(y3);
#undef GELU
        if (g == 0) {
            uint2 ov;
            ov.x = (unsigned)f2bf(y0) | ((unsigned)f2bf(y1) << 16);
            ov.y = (unsigned)f2bf(y2) | ((unsigned)f2bf(y3) << 16);
            hout_bf[(size_t)n * 32 + li] = ov;
        }
    } else {
        if (g == 0)
            *(float4*)&hout_f32[(size_t)n * HDIM + c] = make_float4(y0, y1, y2, y3);
        float4 hwv = *(const float4*)&head_w[c];
        float p = y0 * hwv.x + y1 * hwv.y + y2 * hwv.z + y3 * hwv.w;
#pragma unroll
        for (int o = 1; o < 32; o <<= 1) p += __shfl_xor(p, o);
        if (lane == 0) scores[n] = p + head_b[0];
    }
}

// ---------------- Fully fused layer: agg(H) -> @W -> +b -> LN -> (GELU | head) ------
// 32-node tile, 8 waves / 512 threads, 16.9 KB LDS => occupancy cap 100%
// (4 blocks/CU by thread limit), grid 1563 blocks (6.1/CU). Phase 1: wave w
// aggregates nodes w*4..w*4+3 (pipelined, 4-deep row-load dbuf + next-node csr
// prefetch). Phase 2: wave = row-half (w>>2)*16 x col-quarter (w&3), acc[2].
// Phase 3: +bias store-back via verified gemm_body mapping. Phase 4: verbatim
// agg_ln LayerNorm, 4 nodes/wave. Barriers between phases (all threads reach).
__global__ __launch_bounds__(512) void layer_fused_kernel(
    const uint2* __restrict__ h2, const int* __restrict__ degcnt,
    const ushort* __restrict__ csr16, const float* __restrict__ isd,
    const float* __restrict__ ind, const ushort* __restrict__ bfrag,
    const float* __restrict__ conv_b, const float* __restrict__ ln_g,
    const float* __restrict__ ln_b, uint2* __restrict__ hout_bf,
    float* __restrict__ hout_f32, const float* __restrict__ head_w,
    const float* __restrict__ head_b, float* __restrict__ scores,
    int final_layer) {
    __shared__ float aggsf[32][132];  // f32 rows; +4 pad floats per row (528 B rows)
    int wave = threadIdx.x >> 6, lane = threadIdx.x & 63;
    int g = lane >> 5, li = lane & 31;

    // ---- phase 1: aggregate 4 nodes per wave, pipelined ----
    int nodeBase = blockIdx.x * 32 + wave * 4;
    int deg_c = 0, sj_c = 0;
    float wj_c = 0.f;
    if (nodeBase < N_NODES) {
        deg_c = min(degcnt[nodeBase], SEG);
        int sraw = (int)csr16[nodeBase * SEG + lane];
        sj_c = (lane < deg_c) ? sraw : 0;
        float w = isd[sj_c];
        wj_c = (lane < deg_c) ? w : 0.f;
    }
    for (int it = 0; it < 4; ++it) {
        int n = nodeBase + it;
        int deg = deg_c, sj = sj_c;
        float wj = wj_c;
        // issue next node's deg+csr loads now; finish (isd) after the gather
        int deg_nx = 0, sraw_nx = 0;
        if (it < 3 && (n + 1) < N_NODES) {
            deg_nx = min(degcnt[n + 1], SEG);
            sraw_nx = (int)csr16[(n + 1) * SEG + lane];
        }
        float a0 = 0.f, a1 = 0.f, a2 = 0.f, a3 = 0.f;
        if (n < N_NODES) {
            float isd_n = isd[n], ind_n = ind[n];
            uint2 hv = h2[(size_t)n * 32 + li];
            float e0 = 0.f, e1 = 0.f, e2 = 0.f, e3 = 0.f;
            // preload iteration j=0's rows (tail idx -> row 0, weight 0)
            uint2 u[4];
#pragma unroll
            for (int t = 0; t < 4; ++t) {
                int s = __shfl(sj, 2 * t + g);
                u[t] = h2[(size_t)s * 32 + li];
            }
            for (int j = 0; j < deg; j += 8) {
                uint2 un[4];
                int jn = j + 8;
                bool more = jn < deg;  // wave-uniform
                if (more) {
#pragma unroll
                    for (int t = 0; t < 4; ++t) {
                        int s = __shfl(sj, jn + 2 * t + g);  // jn<=56 -> idx<=63
                        un[t] = h2[(size_t)s * 32 + li];
                    }
                }
#pragma unroll
                for (int t = 0; t < 4; ++t) {
                    float w = __shfl(wj, j + 2 * t + g);
                    float2 q0 = bf2f2(u[t].x), q1 = bf2f2(u[t].y);
                    e0 = fmaf(q0.x, w, e0); e1 = fmaf(q0.y, w, e1);
                    e2 = fmaf(q1.x, w, e2); e3 = fmaf(q1.y, w, e3);
                }
                if (more) { u[0] = un[0]; u[1] = un[1]; u[2] = un[2]; u[3] = un[3]; }
            }
            e0 += __shfl_xor(e0, 32); e1 += __shfl_xor(e1, 32);
            e2 += __shfl_xor(e2, 32); e3 += __shfl_xor(e3, 32);
            float2 h0 = bf2f2(hv.x), h1v = bf2f2(hv.y);
            a0 = fmaf(e0, isd_n, h0.x * ind_n);
            a1 = fmaf(e1, isd_n, h0.y * ind_n);
            a2 = fmaf(e2, isd_n, h1v.x * ind_n);
            a3 = fmaf(e3, isd_n, h1v.y * ind_n);
        }
        if (g == 0)
            *(float4*)&aggsf[wave * 4 + it][li * 4] = make_float4(a0, a1, a2, a3);
        // finish next-node prefetch: mask stale lanes, gather isd
        deg_c = deg_nx;
        sj_c = (lane < deg_nx) ? sraw_nx : 0;
        float w = isd[sj_c];
        wj_c = (lane < deg_nx) ? w : 0.f;
    }
    __syncthreads();  // other waves read these agg rows

    // ---- phase 2: GEMM (split hi/lo bf16 A from f32 LDS) @ (bfrag B) ----
    // wave: row half rtile=(w>>2)*16; col quarter cq=w&3 -> t in {2cq, 2cq+1}
    int quad = lane >> 4, mrow = lane & 15;
    int rtile = (wave >> 2) * 16;
    int cq2 = (wave & 3) * 2;
    floatx4 acc[2];
    acc[0] = (floatx4)0.f;
    acc[1] = (floatx4)0.f;
#pragma unroll
    for (int s = 0; s < 4; ++s) {
        const float* rowp = &aggsf[rtile + mrow][s * 32 + quad * 8];
        float4 pa = *(const float4*)rowp;
        float4 pb = *(const float4*)(rowp + 4);
        float p[8] = {pa.x, pa.y, pa.z, pa.w, pb.x, pb.y, pb.z, pb.w};
        union { short8 v; ushort u[8]; } hi, lo;
#pragma unroll
        for (int j = 0; j < 8; ++j) {
            ushort h = f2bf(p[j]);
            hi.u[j] = h;
            float hf = __uint_as_float((unsigned)h << 16);
            lo.u[j] = f2bf(p[j] - hf);  // exact residual (Sterbenz), then 1 round
        }
#pragma unroll
        for (int t4 = 0; t4 < 2; ++t4) {
            int t = cq2 + t4;
            short8 bf = *(const short8*)&bfrag[(size_t)(((s * 8 + t) * 64) + lane) * 8];
            acc[t4] = __builtin_amdgcn_mfma_f32_16x16x32_bf16(lo.v, bf, acc[t4], 0, 0, 0);
            acc[t4] = __builtin_amdgcn_mfma_f32_16x16x32_bf16(hi.v, bf, acc[t4], 0, 0, 0);
        }
    }
    __syncthreads();  // all reads of agg rows done before overwrite

    // ---- phase 3: +bias, store acc back to LDS rows (verified gemm_body mapping) ----
    {
        float cb[2];
#pragma unroll
        for (int t4 = 0; t4 < 2; ++t4) cb[t4] = conv_b[(cq2 + t4) * 16 + mrow];
#pragma unroll
        for (int t4 = 0; t4 < 2; ++t4)
#pragma unroll
            for (int r = 0; r < 4; ++r)
                aggsf[rtile + quad * 4 + r][(cq2 + t4) * 16 + mrow] = acc[t4][r] + cb[t4];
    }
    __syncthreads();  // LN reads full rows

    // ---- phase 4: per-node LN from LDS — verbatim agg_ln pattern, 4 nodes/wave ----
    int c = li * 4;
    float4 gv = *(const float4*)&ln_g[c];
    float4 bv = *(const float4*)&ln_b[c];
    float4 hwv = *(const float4*)&head_w[c];
    for (int it = 0; it < 4; ++it) {
        int row = wave * 4 + it;
        int n = blockIdx.x * 32 + row;
        if (n >= N_NODES) continue;  // wave-uniform
        float4 v = *(const float4*)&aggsf[row][c];
        float a0 = v.x, a1 = v.y, a2 = v.z, a3 = v.w;

        float sum = a0 + a1 + a2 + a3;
#pragma unroll
        for (int o = 1; o < 32; o <<= 1) sum += __shfl_xor(sum, o);
        float mu = sum * (1.0f / HDIM);
        float d0 = a0 - mu, d1 = a1 - mu, d2 = a2 - mu, d3 = a3 - mu;
        float vs = d0 * d0 + d1 * d1 + d2 * d2 + d3 * d3;
#pragma unroll
        for (int o = 1; o < 32; o <<= 1) vs += __shfl_xor(vs, o);
        float rstd = rsqrtf(vs * (1.0f / HDIM) + LN_EPS);
        float y0 = fmaf(d0 * rstd, gv.x, bv.x);
        float y1 = fmaf(d1 * rstd, gv.y, bv.y);
        float y2 = fmaf(d2 * rstd, gv.z, bv.z);
        float y3 = fmaf(d3 * rstd, gv.w, bv.w);

        if (!final_layer) {
#define GELU(v) ((v) = 0.5f * (v) * (1.0f + erff((v) * 0.70710678118654752f)))
            GELU(y0); GELU(y1); GELU(y2); GELU(y3);
#undef GELU
            if (g == 0) {
                uint2 ov;
                ov.x = (unsigned)f2bf(y0) | ((unsigned)f2bf(y1) << 16);
                ov.y = (unsigned)f2bf(y2) | ((unsigned)f2bf(y3) << 16);
                hout_bf[(size_t)n * 32 + li] = ov;
            }
        } else {
            if (g == 0)
                *(float4*)&hout_f32[(size_t)n * HDIM + c] = make_float4(y0, y1, y2, y3);
            float p = y0 * hwv.x + y1 * hwv.y + y2 * hwv.z + y3 * hwv.w;
#pragma unroll
            for (int o = 1; o < 32; o <<= 1) p += __shfl_xor(p, o);
            if (lane == 0) scores[n] = p + head_b[0];
        }
    }
}

// ---------------- host ----------------

extern "C" void kernel_launch(void* const* d_in, const int* in_sizes, int n_in,
                              void* d_out, int out_size, void* d_ws, size_t ws_size,
                              hipStream_t stream) {
    const float* x      = (const float*)d_in[0];
    const int*   eidx   = (const int*)d_in[1];
    const float* conv_w = (const float*)d_in[2];
    const float* conv_b = (const float*)d_in[3];
    const float* ln_g   = (const float*)d_in[4];
    const float* ln_b   = (const float*)d_in[5];
    const float* head_w = (const float*)d_in[6];
    const float* head_b = (const float*)d_in[7];
    float* out = (float*)d_out;  // [N scores][N*H h]

    const int* src = eidx;
    const int* dst = eidx + N_EDGES;

    char* ws = (char*)d_ws;
    size_t o = 0;
    auto alloc = [&](size_t elems) {  // elems of 4 bytes
        void* p = ws + o * 4;
        o += (elems + 15) & ~(size_t)15;
        return p;
    };
    int*      cnt      = (int*)alloc(N_NODES);
    float*    isd      = (float*)alloc(N_NODES);
    float*    ind      = (float*)alloc(N_NODES);
    ushort*   csr16    = (ushort*)alloc((size_t)N_NODES * SEG / 2);
    ushort*   bfrag    = (ushort*)alloc(NLAYERS * 4 * 8 * 64 * 8 / 2);
    unsigned* hw       = (unsigned*)alloc((size_t)N_NODES * 64);   // bf16 N x 128
    unsigned* hbuf     = (unsigned*)alloc((size_t)N_NODES * 64);   // bf16 N x 128

    hipMemsetAsync(cnt, 0, N_NODES * sizeof(int), stream);
    bprep_kernel<<<(NLAYERS * 4 * 8 * 64 + 255) / 256, 256, 0, stream>>>(conv_w, bfrag);
    fused0_kernel<<<FILLB + GEMMB, 256, 0, stream>>>(src, dst, cnt, csr16, x, bfrag,
                                                     (ushort*)hw);
    isd_kernel<<<(N_NODES + 255) / 256, 256, 0, stream>>>(cnt, isd, ind);

    // layer 0: aggregate hw0 (= x @ W0, computed under the fill) + LN + GELU -> hbuf
    agg_ln_kernel<<<(N_NODES + 3) / 4, 256, 0, stream>>>(
        (const uint2*)hw, cnt, csr16, isd, ind,
        conv_b, ln_g, ln_b,
        (uint2*)hbuf, out + N_NODES, head_w, head_b, out, 0);

    // layers 1..3: fused agg -> GEMM -> LN (+GELU | +head), ping-pong hbuf/hw
    const unsigned* hin = hbuf;
    unsigned* hnext = hw;
    for (int l = 1; l < NLAYERS; ++l) {
        const ushort* bl = bfrag + (size_t)l * 4 * 8 * 64 * 8;
        int fin = (l == NLAYERS - 1) ? 1 : 0;
        layer_fused_kernel<<<LFB, 512, 0, stream>>>(
            (const uint2*)hin, cnt, csr16, isd, ind, bl,
            conv_b + (size_t)l * HDIM, ln_g + (size_t)l * HDIM, ln_b + (size_t)l * HDIM,
            (uint2*)hnext, out + N_NODES, head_w, head_b, out, fin);
        const unsigned* tmp = hin;
        hin = hnext;
        hnext = (unsigned*)tmp;
    }
}

// Round 7
// 340.160 us; speedup vs baseline: 1.1792x; 1.0638x over previous
//
#include <hip/hip_runtime.h>
#include <math.h>

#define N_NODES 50000
#define N_EDGES 800000
#define HDIM 128
#define NLAYERS 4
#define LN_EPS 1e-5f
#define EHALF (N_EDGES / 2)
#define SEG 64   // CSR slots per node (P(deg>64) ~ 1e-19 for Poisson(16))
#define FILLB ((EHALF + 255) / 256)      // 1563 fill blocks (2 edges/thread)
#define GEMMB ((N_NODES + 63) / 64)      // 782 gemm blocks
#define LFB ((N_NODES + 31) / 32)        // 1563 fused-layer blocks (32-node tiles)

typedef __attribute__((ext_vector_type(8))) short short8;
typedef __attribute__((ext_vector_type(4))) float floatx4;

__device__ __forceinline__ ushort f2bf(float x) {
    unsigned b = __float_as_uint(x);
    unsigned r = b + 0x7fffu + ((b >> 16) & 1u);
    return (ushort)(r >> 16);
}
__device__ __forceinline__ float2 bf2f2(unsigned u) {
    return make_float2(__uint_as_float(u << 16), __uint_as_float(u & 0xffff0000u));
}

// ---------------- prep: zero cnt + W -> MFMA B-fragment layout (bf16) ----------------
__global__ __launch_bounds__(256) void prep_kernel(const float* __restrict__ W,
                                                   ushort* __restrict__ bfrag,
                                                   int* __restrict__ cnt) {
    int idx = blockIdx.x * 256 + threadIdx.x;
    if (idx < N_NODES) cnt[idx] = 0;
    if (idx < NLAYERS * 4 * 8 * 64) {
        int lane = idx & 63;
        int t = (idx >> 6) & 7;
        int s = (idx >> 9) & 3;
        int l = idx >> 11;
        int n = t * 16 + (lane & 15);
        int kb = s * 32 + (lane >> 4) * 8;
        const float* Wl = W + (size_t)l * HDIM * HDIM;
        union { uint4 q; ushort u[8]; } o;
#pragma unroll
        for (int j = 0; j < 8; ++j) o.u[j] = f2bf(Wl[(size_t)(kb + j) * HDIM + n]);
        *(uint4*)&bfrag[(size_t)idx * 8] = o.q;
    }
}

// ---------------- CSR build: padded segments, single scattered pass ----------------
// 2 edges/thread, 1563 blocks: ~24 fill waves/CU for more outstanding atomics.
__device__ __forceinline__ void fill_body(int bid, int tid, const int* __restrict__ src,
                                          const int* __restrict__ dst, int* __restrict__ cnt,
                                          ushort* __restrict__ csr16) {
    int t = bid * 256 + tid;
    if (t >= EHALF) return;
    int s0 = src[t],         d0 = dst[t];
    int s1 = src[t + EHALF], d1 = dst[t + EHALF];
    int p0 = atomicAdd(&cnt[d0], 1);
    int p1 = atomicAdd(&cnt[d1], 1);
    if (p0 < SEG) csr16[d0 * SEG + p0] = (ushort)s0;
    if (p1 < SEG) csr16[d1 * SEG + p1] = (ushort)s1;
}

// ---------------- GEMM body: hw_bf16 = A @ W  via MFMA 16x16x32 bf16 ----------------
template <bool A_FP32>
__device__ __forceinline__ void gemm_body(int bid, int tid, const void* __restrict__ Av,
                                          const ushort* __restrict__ bfrag,
                                          ushort* __restrict__ out) {
    int wave = tid >> 6, lane = tid & 63;
    int quad = lane >> 4, mrow = lane & 15;
    int rowBase = bid * 64 + wave * 16;
    int arow = rowBase + mrow;
    bool aok = arow < N_NODES;

    floatx4 acc[8];
#pragma unroll
    for (int t = 0; t < 8; ++t) acc[t] = (floatx4)0.f;

#pragma unroll
    for (int s = 0; s < 4; ++s) {
        union { short8 v; ushort u[8]; } af;
        if (A_FP32) {
            const float* A = (const float*)Av;
            if (aok) {
                const float* p = &A[(size_t)arow * HDIM + s * 32 + quad * 8];
#pragma unroll
                for (int j = 0; j < 8; ++j) af.u[j] = f2bf(p[j]);
            } else {
#pragma unroll
                for (int j = 0; j < 8; ++j) af.u[j] = 0;
            }
        } else {
            const ushort* A = (const ushort*)Av;
            if (aok) {
                af.v = *(const short8*)&A[(size_t)arow * HDIM + s * 32 + quad * 8];
            } else {
#pragma unroll
                for (int j = 0; j < 8; ++j) af.u[j] = 0;
            }
        }
#pragma unroll
        for (int t = 0; t < 8; ++t) {
            short8 bf = *(const short8*)&bfrag[(size_t)(((s * 8 + t) * 64) + lane) * 8];
            acc[t] = __builtin_amdgcn_mfma_f32_16x16x32_bf16(af.v, bf, acc[t], 0, 0, 0);
        }
    }
#pragma unroll
    for (int t = 0; t < 8; ++t) {
#pragma unroll
        for (int r = 0; r < 4; ++r) {
            int row = rowBase + quad * 4 + r;
            if (row < N_NODES) out[(size_t)row * HDIM + t * 16 + mrow] = f2bf(acc[t][r]);
        }
    }
}

// Fused: fill (independent) overlapped with layer-0 GEMM (independent).
__global__ __launch_bounds__(256) void fused0_kernel(
    const int* __restrict__ src, const int* __restrict__ dst, int* __restrict__ cnt,
    ushort* __restrict__ csr16, const float* __restrict__ x,
    const ushort* __restrict__ bfrag0, ushort* __restrict__ hw) {
    if (blockIdx.x < FILLB)
        fill_body(blockIdx.x, threadIdx.x, src, dst, cnt, csr16);
    else
        gemm_body<true>(blockIdx.x - FILLB, threadIdx.x, x, bfrag0, hw);
}

// ---------------- Fused aggregate + self-loop + bias + LN (+GELU / +head) ----------------
// Layer 0 only. isd/ind computed on the fly from cnt (cnt is L2-hot, 200 KB).
__global__ __launch_bounds__(256) void agg_ln_kernel(
    const uint2* __restrict__ hw2, const int* __restrict__ degcnt,
    const ushort* __restrict__ csr16, const float* __restrict__ conv_b,
    const float* __restrict__ ln_g, const float* __restrict__ ln_b,
    uint2* __restrict__ hout_bf, float* __restrict__ hout_f32,
    const float* __restrict__ head_w, const float* __restrict__ head_b,
    float* __restrict__ scores, int final_layer) {
    int wave = threadIdx.x >> 6;
    int lane = threadIdx.x & 63;
    int g = lane >> 5;   // edge-parity group
    int li = lane & 31;  // lane in group; owns cols li*4 .. li*4+3
    int n = blockIdx.x * 4 + wave;
    if (n >= N_NODES) return;
    int c = li * 4;

    int rawc = degcnt[n];
    float dsum = (float)rawc + 1.0f;       // self-loop
    float isd_n = rsqrtf(dsum);
    float ind_n = isd_n * isd_n;           // == 1/d up to 2 ulp
    int rs = n * SEG;
    int deg = min(rawc, SEG);

    float e0 = 0.f, e1 = 0.f, e2 = 0.f, e3 = 0.f;
    int sj = 0;
    float wj = 0.f;
    if (lane < deg) sj = (int)csr16[rs + lane];
    {
        float w = rsqrtf((float)degcnt[sj] + 1.0f);
        wj = (lane < deg) ? w : 0.f;
    }
    for (int j = 0; j < deg; j += 8) {
#pragma unroll
        for (int t = 0; t < 4; ++t) {
            int idx = j + 2 * t + g;
            int s = __shfl(sj, idx);
            float w = __shfl(wj, idx);
            uint2 u = hw2[(size_t)s * 32 + li];
            float2 q0 = bf2f2(u.x), q1 = bf2f2(u.y);
            e0 = fmaf(q0.x, w, e0); e1 = fmaf(q0.y, w, e1);
            e2 = fmaf(q1.x, w, e2); e3 = fmaf(q1.y, w, e3);
        }
    }
    e0 += __shfl_xor(e0, 32); e1 += __shfl_xor(e1, 32);
    e2 += __shfl_xor(e2, 32); e3 += __shfl_xor(e3, 32);

    uint2 hv = hw2[(size_t)n * 32 + li];
    float2 h0 = bf2f2(hv.x), h1 = bf2f2(hv.y);
    float4 cb = *(const float4*)&conv_b[c];
    float a0 = fmaf(e0, isd_n, fmaf(h0.x, ind_n, cb.x));
    float a1 = fmaf(e1, isd_n, fmaf(h0.y, ind_n, cb.y));
    float a2 = fmaf(e2, isd_n, fmaf(h1.x, ind_n, cb.z));
    float a3 = fmaf(e3, isd_n, fmaf(h1.y, ind_n, cb.w));

    float sum = a0 + a1 + a2 + a3;
#pragma unroll
    for (int o = 1; o < 32; o <<= 1) sum += __shfl_xor(sum, o);
    float mu = sum * (1.0f / HDIM);
    float d0 = a0 - mu, d1 = a1 - mu, d2 = a2 - mu, d3 = a3 - mu;
    float vs = d0 * d0 + d1 * d1 + d2 * d2 + d3 * d3;
#pragma unroll
    for (int o = 1; o < 32; o <<= 1) vs += __shfl_xor(vs, o);
    float rstd = rsqrtf(vs * (1.0f / HDIM) + LN_EPS);
    float4 gv = *(const float4*)&ln_g[c];
    float4 bv = *(const float4*)&ln_b[c];
    float y0 = fmaf(d0 * rstd, gv.x, bv.x);
    float y1 = fmaf(d1 * rstd, gv.y, bv.y);
    float y2 = fmaf(d2 * rstd, gv.z, bv.z);
    float y3 = fmaf(d3 * rstd, gv.w, bv.w);

    if (!final_layer) {
#define GELU(v) ((v) = 0.5f * (v) * (1.0f + erff((v) * 0.70710678118654752f)))
        GELU(y0); GELU(y1); GELU(y2); GELU(y3);
#undef GELU
        if (g == 0) {
            uint2 ov;
            ov.x = (unsigned)f2bf(y0) | ((unsigned)f2bf(y1) << 16);
            ov.y = (unsigned)f2bf(y2) | ((unsigned)f2bf(y3) << 16);
            hout_bf[(size_t)n * 32 + li] = ov;
        }
    } else {
        if (g == 0)
            *(float4*)&hout_f32[(size_t)n * HDIM + c] = make_float4(y0, y1, y2, y3);
        float4 hwv = *(const float4*)&head_w[c];
        float p = y0 * hwv.x + y1 * hwv.y + y2 * hwv.z + y3 * hwv.w;
#pragma unroll
        for (int o = 1; o < 32; o <<= 1) p += __shfl_xor(p, o);
        if (lane == 0) scores[n] = p + head_b[0];
    }
}

// ---------------- Fully fused layer: agg(H) -> @W -> +b -> LN -> (GELU | head) ------
// 32-node tile, 8 waves / 512 threads, 16.9 KB LDS, grid 1563. isd/ind on the fly.
__global__ __launch_bounds__(512) void layer_fused_kernel(
    const uint2* __restrict__ h2, const int* __restrict__ degcnt,
    const ushort* __restrict__ csr16, const ushort* __restrict__ bfrag,
    const float* __restrict__ conv_b, const float* __restrict__ ln_g,
    const float* __restrict__ ln_b, uint2* __restrict__ hout_bf,
    float* __restrict__ hout_f32, const float* __restrict__ head_w,
    const float* __restrict__ head_b, float* __restrict__ scores,
    int final_layer) {
    __shared__ float aggsf[32][132];  // f32 rows; +4 pad floats per row (528 B rows)
    int wave = threadIdx.x >> 6, lane = threadIdx.x & 63;
    int g = lane >> 5, li = lane & 31;

    // ---- phase 1: aggregate 4 nodes per wave, pipelined ----
    int nodeBase = blockIdx.x * 32 + wave * 4;
    int cnt_c = 0, sj_c = 0;
    float wj_c = 0.f;
    if (nodeBase < N_NODES) {
        cnt_c = degcnt[nodeBase];
        int degp = min(cnt_c, SEG);
        int sraw = (int)csr16[nodeBase * SEG + lane];
        sj_c = (lane < degp) ? sraw : 0;
        float w = rsqrtf((float)degcnt[sj_c] + 1.0f);
        wj_c = (lane < degp) ? w : 0.f;
    }
    for (int it = 0; it < 4; ++it) {
        int n = nodeBase + it;
        int deg = min(cnt_c, SEG), sj = sj_c;
        float dsum = (float)cnt_c + 1.0f;
        float wj = wj_c;
        // issue next node's deg+csr loads now; finish (degcnt gather) after
        int cnt_nx = 0, sraw_nx = 0;
        if (it < 3 && (n + 1) < N_NODES) {
            cnt_nx = degcnt[n + 1];
            sraw_nx = (int)csr16[(n + 1) * SEG + lane];
        }
        float a0 = 0.f, a1 = 0.f, a2 = 0.f, a3 = 0.f;
        if (n < N_NODES) {
            float isd_n = rsqrtf(dsum);
            float ind_n = isd_n * isd_n;
            uint2 hv = h2[(size_t)n * 32 + li];
            float e0 = 0.f, e1 = 0.f, e2 = 0.f, e3 = 0.f;
            // preload iteration j=0's rows (tail idx -> row 0, weight 0)
            uint2 u[4];
#pragma unroll
            for (int t = 0; t < 4; ++t) {
                int s = __shfl(sj, 2 * t + g);
                u[t] = h2[(size_t)s * 32 + li];
            }
            for (int j = 0; j < deg; j += 8) {
                uint2 un[4];
                int jn = j + 8;
                bool more = jn < deg;  // wave-uniform
                if (more) {
#pragma unroll
                    for (int t = 0; t < 4; ++t) {
                        int s = __shfl(sj, jn + 2 * t + g);  // jn<=56 -> idx<=63
                        un[t] = h2[(size_t)s * 32 + li];
                    }
                }
#pragma unroll
                for (int t = 0; t < 4; ++t) {
                    float w = __shfl(wj, j + 2 * t + g);
                    float2 q0 = bf2f2(u[t].x), q1 = bf2f2(u[t].y);
                    e0 = fmaf(q0.x, w, e0); e1 = fmaf(q0.y, w, e1);
                    e2 = fmaf(q1.x, w, e2); e3 = fmaf(q1.y, w, e3);
                }
                if (more) { u[0] = un[0]; u[1] = un[1]; u[2] = un[2]; u[3] = un[3]; }
            }
            e0 += __shfl_xor(e0, 32); e1 += __shfl_xor(e1, 32);
            e2 += __shfl_xor(e2, 32); e3 += __shfl_xor(e3, 32);
            float2 h0 = bf2f2(hv.x), h1v = bf2f2(hv.y);
            a0 = fmaf(e0, isd_n, h0.x * ind_n);
            a1 = fmaf(e1, isd_n, h0.y * ind_n);
            a2 = fmaf(e2, isd_n, h1v.x * ind_n);
            a3 = fmaf(e3, isd_n, h1v.y * ind_n);
        }
        if (g == 0)
            *(float4*)&aggsf[wave * 4 + it][li * 4] = make_float4(a0, a1, a2, a3);
        // finish next-node prefetch: mask stale lanes, gather degcnt
        int degp = min(cnt_nx, SEG);
        cnt_c = cnt_nx;
        sj_c = (lane < degp) ? sraw_nx : 0;
        float w = rsqrtf((float)degcnt[sj_c] + 1.0f);
        wj_c = (lane < degp) ? w : 0.f;
    }
    __syncthreads();  // other waves read these agg rows

    // ---- phase 2: GEMM (split hi/lo bf16 A from f32 LDS) @ (bfrag B) ----
    // wave: row half rtile=(w>>2)*16; col quarter cq=w&3 -> t in {2cq, 2cq+1}
    int quad = lane >> 4, mrow = lane & 15;
    int rtile = (wave >> 2) * 16;
    int cq2 = (wave & 3) * 2;
    floatx4 acc[2];
    acc[0] = (floatx4)0.f;
    acc[1] = (floatx4)0.f;
#pragma unroll
    for (int s = 0; s < 4; ++s) {
        const float* rowp = &aggsf[rtile + mrow][s * 32 + quad * 8];
        float4 pa = *(const float4*)rowp;
        float4 pb = *(const float4*)(rowp + 4);
        float p[8] = {pa.x, pa.y, pa.z, pa.w, pb.x, pb.y, pb.z, pb.w};
        union { short8 v; ushort u[8]; } hi, lo;
#pragma unroll
        for (int j = 0; j < 8; ++j) {
            ushort h = f2bf(p[j]);
            hi.u[j] = h;
            float hf = __uint_as_float((unsigned)h << 16);
            lo.u[j] = f2bf(p[j] - hf);  // exact residual (Sterbenz), then 1 round
        }
#pragma unroll
        for (int t4 = 0; t4 < 2; ++t4) {
            int t = cq2 + t4;
            short8 bf = *(const short8*)&bfrag[(size_t)(((s * 8 + t) * 64) + lane) * 8];
            acc[t4] = __builtin_amdgcn_mfma_f32_16x16x32_bf16(lo.v, bf, acc[t4], 0, 0, 0);
            acc[t4] = __builtin_amdgcn_mfma_f32_16x16x32_bf16(hi.v, bf, acc[t4], 0, 0, 0);
        }
    }
    __syncthreads();  // all reads of agg rows done before overwrite

    // ---- phase 3: +bias, store acc back to LDS rows (verified gemm_body mapping) ----
    {
        float cb[2];
#pragma unroll
        for (int t4 = 0; t4 < 2; ++t4) cb[t4] = conv_b[(cq2 + t4) * 16 + mrow];
#pragma unroll
        for (int t4 = 0; t4 < 2; ++t4)
#pragma unroll
            for (int r = 0; r < 4; ++r)
                aggsf[rtile + quad * 4 + r][(cq2 + t4) * 16 + mrow] = acc[t4][r] + cb[t4];
    }
    __syncthreads();  // LN reads full rows

    // ---- phase 4: per-node LN from LDS — verbatim agg_ln pattern, 4 nodes/wave ----
    int c = li * 4;
    float4 gv = *(const float4*)&ln_g[c];
    float4 bv = *(const float4*)&ln_b[c];
    float4 hwv = *(const float4*)&head_w[c];
    for (int it = 0; it < 4; ++it) {
        int row = wave * 4 + it;
        int n = blockIdx.x * 32 + row;
        if (n >= N_NODES) continue;  // wave-uniform
        float4 v = *(const float4*)&aggsf[row][c];
        float a0 = v.x, a1 = v.y, a2 = v.z, a3 = v.w;

        float sum = a0 + a1 + a2 + a3;
#pragma unroll
        for (int o = 1; o < 32; o <<= 1) sum += __shfl_xor(sum, o);
        float mu = sum * (1.0f / HDIM);
        float d0 = a0 - mu, d1 = a1 - mu, d2 = a2 - mu, d3 = a3 - mu;
        float vs = d0 * d0 + d1 * d1 + d2 * d2 + d3 * d3;
#pragma unroll
        for (int o = 1; o < 32; o <<= 1) vs += __shfl_xor(vs, o);
        float rstd = rsqrtf(vs * (1.0f / HDIM) + LN_EPS);
        float y0 = fmaf(d0 * rstd, gv.x, bv.x);
        float y1 = fmaf(d1 * rstd, gv.y, bv.y);
        float y2 = fmaf(d2 * rstd, gv.z, bv.z);
        float y3 = fmaf(d3 * rstd, gv.w, bv.w);

        if (!final_layer) {
#define GELU(v) ((v) = 0.5f * (v) * (1.0f + erff((v) * 0.70710678118654752f)))
            GELU(y0); GELU(y1); GELU(y2); GELU(y3);
#undef GELU
            if (g == 0) {
                uint2 ov;
                ov.x = (unsigned)f2bf(y0) | ((unsigned)f2bf(y1) << 16);
                ov.y = (unsigned)f2bf(y2) | ((unsigned)f2bf(y3) << 16);
                hout_bf[(size_t)n * 32 + li] = ov;
            }
        } else {
            if (g == 0)
                *(float4*)&hout_f32[(size_t)n * HDIM + c] = make_float4(y0, y1, y2, y3);
            float p = y0 * hwv.x + y1 * hwv.y + y2 * hwv.z + y3 * hwv.w;
#pragma unroll
            for (int o = 1; o < 32; o <<= 1) p += __shfl_xor(p, o);
            if (lane == 0) scores[n] = p + head_b[0];
        }
    }
}

// ---------------- host ----------------

extern "C" void kernel_launch(void* const* d_in, const int* in_sizes, int n_in,
                              void* d_out, int out_size, void* d_ws, size_t ws_size,
                              hipStream_t stream) {
    const float* x      = (const float*)d_in[0];
    const int*   eidx   = (const int*)d_in[1];
    const float* conv_w = (const float*)d_in[2];
    const float* conv_b = (const float*)d_in[3];
    const float* ln_g   = (const float*)d_in[4];
    const float* ln_b   = (const float*)d_in[5];
    const float* head_w = (const float*)d_in[6];
    const float* head_b = (const float*)d_in[7];
    float* out = (float*)d_out;  // [N scores][N*H h]

    const int* src = eidx;
    const int* dst = eidx + N_EDGES;

    char* ws = (char*)d_ws;
    size_t o = 0;
    auto alloc = [&](size_t elems) {  // elems of 4 bytes
        void* p = ws + o * 4;
        o += (elems + 15) & ~(size_t)15;
        return p;
    };
    int*      cnt      = (int*)alloc(N_NODES);
    ushort*   csr16    = (ushort*)alloc((size_t)N_NODES * SEG / 2);
    ushort*   bfrag    = (ushort*)alloc(NLAYERS * 4 * 8 * 64 * 8 / 2);
    unsigned* hw       = (unsigned*)alloc((size_t)N_NODES * 64);   // bf16 N x 128
    unsigned* hbuf     = (unsigned*)alloc((size_t)N_NODES * 64);   // bf16 N x 128

    // prep: zero cnt + build W fragments (one dispatch)
    prep_kernel<<<(N_NODES + 255) / 256, 256, 0, stream>>>(conv_w, bfrag, cnt);
    // fill CSR (1563 blocks) overlapped with layer-0 GEMM (782 blocks)
    fused0_kernel<<<FILLB + GEMMB, 256, 0, stream>>>(src, dst, cnt, csr16, x, bfrag,
                                                     (ushort*)hw);

    // layer 0: aggregate hw0 (= x @ W0, computed under the fill) + LN + GELU -> hbuf
    agg_ln_kernel<<<(N_NODES + 3) / 4, 256, 0, stream>>>(
        (const uint2*)hw, cnt, csr16,
        conv_b, ln_g, ln_b,
        (uint2*)hbuf, out + N_NODES, head_w, head_b, out, 0);

    // layers 1..3: fused agg -> GEMM -> LN (+GELU | +head), ping-pong hbuf/hw
    const unsigned* hin = hbuf;
    unsigned* hnext = hw;
    for (int l = 1; l < NLAYERS; ++l) {
        const ushort* bl = bfrag + (size_t)l * 4 * 8 * 64 * 8;
        int fin = (l == NLAYERS - 1) ? 1 : 0;
        layer_fused_kernel<<<LFB, 512, 0, stream>>>(
            (const uint2*)hin, cnt, csr16, bl,
            conv_b + (size_t)l * HDIM, ln_g + (size_t)l * HDIM, ln_b + (size_t)l * HDIM,
            (uint2*)hnext, out + N_NODES, head_w, head_b, out, fin);
        const unsigned* tmp = hin;
        hin = hnext;
        hnext = (unsigned*)tmp;
    }
}